// Round 1
// baseline (199.273 us; speedup 1.0000x reference)
//
#include <hip/hip_runtime.h>
#include <stdint.h>

typedef __attribute__((ext_vector_type(8))) short short8;
typedef __attribute__((ext_vector_type(4))) float f32x4;

#define TC     128      // t-elements per LDS B chunk
#define BROW   136      // shorts per B row in LDS (128 data + 8 pad -> 272 B, 16B aligned, 2-way banks)
#define XROW   136      // shorts per transposed-X row (128 z + 8 pad)
#define NCHUNK 32       // 4096 / TC

__device__ __forceinline__ unsigned short f2bf_rne(float f) {
  unsigned u = __builtin_bit_cast(unsigned, f);
  u += 0x7fffu + ((u >> 16) & 1u);
  return (unsigned short)(u >> 16);
}
__device__ __forceinline__ float bf2f(unsigned short s) {
  unsigned u = ((unsigned)s) << 16;
  return __builtin_bit_cast(float, u);
}
// pack two f32 -> two bf16 (truncate) in one v_perm_b32; lo short = p0
__device__ __forceinline__ unsigned pack_bf2(float p0, float p1) {
  return __builtin_amdgcn_perm(__builtin_bit_cast(unsigned, p1),
                               __builtin_bit_cast(unsigned, p0), 0x07060302u);
}

// ---------------- phase 1: M~[k][t] = sum_w wgt[w]*mix[w][k][t], bf16 ----------------
__global__ __launch_bounds__(256) void prep_kernel(const float* __restrict__ mix,
                                                   const float* __restrict__ wgt,
                                                   unsigned short* __restrict__ Bp) {
  const int t4 = blockIdx.x * 256 + threadIdx.x;  // 0..65535, 4 elems each
  const float4* m4 = (const float4*)mix;
  float ax = 0.f, ay = 0.f, az = 0.f, aw = 0.f;
#pragma unroll
  for (int w = 0; w < 32; ++w) {
    const float s = wgt[w];
    const float4 v = m4[w * 65536 + t4];
    ax += s * v.x; ay += s * v.y; az += s * v.z; aw += s * v.w;
  }
  ushort4 r;
  r.x = f2bf_rne(ax); r.y = f2bf_rne(ay); r.z = f2bf_rne(az); r.w = f2bf_rne(aw);
  ((ushort4*)Bp)[t4] = r;
}

// ---------------- phase 2: out[z][k] = sum_t V[z,t]*M~[k,t], V generated in-register ----------------
__global__ __launch_bounds__(256, 3) void gemm_kernel(const float* __restrict__ X,
                                                      const unsigned short* __restrict__ Bp,
                                                      float* __restrict__ out) {
  __shared__ unsigned short ldsB[2][64 * BROW];  // [buf][k_out row][t-chunk]
  __shared__ unsigned short ldsX[64 * XROW];     // transposed bf16 X: [feat i][z-local]

  const int tid  = threadIdx.x;
  const int lane = tid & 63;
  const int wv   = tid >> 6;    // wave 0..3, handles 32 z-rows
  const int m    = lane & 15;
  const int q    = lane >> 4;
  const int zblk = blockIdx.x * 128;

  // stage transposed bf16 X tile [64 feats][128 z]
  {
    const float4* X4 = (const float4*)(X + (size_t)zblk * 64);
#pragma unroll
    for (int it = 0; it < 8; ++it) {
      const int lin = tid + it * 256;  // 0..2047
      const int z   = lin >> 4;        // 0..127
      const int c4  = lin & 15;        // 0..15
      const float4 v = X4[z * 16 + c4];
      ldsX[(c4 * 4 + 0) * XROW + z] = f2bf_rne(v.x);
      ldsX[(c4 * 4 + 1) * XROW + z] = f2bf_rne(v.y);
      ldsX[(c4 * 4 + 2) * XROW + z] = f2bf_rne(v.z);
      ldsX[(c4 * 4 + 3) * XROW + z] = f2bf_rne(v.w);
    }
  }
  // stage B chunk 0 into buf 0
  {
#pragma unroll
    for (int it = 0; it < 4; ++it) {
      const int lin = tid + it * 256;  // 0..1023
      const int row = lin >> 4;        // k_out 0..63
      const int cc  = lin & 15;
      const uint4 v = *(const uint4*)(Bp + row * 4096 + cc * 8);
      *(uint4*)(&ldsB[0][row * BROW + cc * 8]) = v;
    }
  }

  // per-lane fp32 j-cache: x[z_row, q*8..q*8+7] and x[z_row, 32+q*8..+7], both z-frags
  float jv0[16], jv1[16];
  {
    const float4* X4 = (const float4*)X;
    const int zg0 = zblk + wv * 32 + m;
    const int zg1 = zg0 + 16;
#pragma unroll
    for (int h = 0; h < 2; ++h) {
      float4 a = X4[zg0 * 16 + h * 8 + q * 2];
      float4 b = X4[zg0 * 16 + h * 8 + q * 2 + 1];
      jv0[h*8+0]=a.x; jv0[h*8+1]=a.y; jv0[h*8+2]=a.z; jv0[h*8+3]=a.w;
      jv0[h*8+4]=b.x; jv0[h*8+5]=b.y; jv0[h*8+6]=b.z; jv0[h*8+7]=b.w;
      a = X4[zg1 * 16 + h * 8 + q * 2];
      b = X4[zg1 * 16 + h * 8 + q * 2 + 1];
      jv1[h*8+0]=a.x; jv1[h*8+1]=a.y; jv1[h*8+2]=a.z; jv1[h*8+3]=a.w;
      jv1[h*8+4]=b.x; jv1[h*8+5]=b.y; jv1[h*8+6]=b.z; jv1[h*8+7]=b.w;
    }
  }

  f32x4 acc0[4], acc1[4];
#pragma unroll
  for (int g = 0; g < 4; ++g) {
    acc0[g] = f32x4{0.f, 0.f, 0.f, 0.f};
    acc1[g] = f32x4{0.f, 0.f, 0.f, 0.f};
  }

  __syncthreads();

  for (int c = 0; c < NCHUNK; ++c) {
    // prefetch next B chunk (global -> regs); latency hidden by compute below
    uint4 pre[4];
    if (c + 1 < NCHUNK) {
#pragma unroll
      for (int it = 0; it < 4; ++it) {
        const int lin = tid + it * 256;
        const int row = lin >> 4;
        const int cc  = lin & 15;
        pre[it] = *(const uint4*)(Bp + row * 4096 + (c + 1) * TC + cc * 8);
      }
    }
    const unsigned short* Bl = ldsB[c & 1];
#pragma unroll
    for (int il = 0; il < 2; ++il) {
      const int ig = c * 2 + il;  // global i
      const int xb = ig * XROW + wv * 32 + m;
      const float s0 = bf2f(ldsX[xb]);        // x[z0, i]
      const float s1 = bf2f(ldsX[xb + 16]);   // x[z1, i]
#pragma unroll
      for (int h = 0; h < 2; ++h) {
        const unsigned short* bb = Bl + m * BROW + il * 64 + h * 32 + q * 8;
        const short8 b0 = *(const short8*)(bb);
        const short8 b1 = *(const short8*)(bb + 16 * BROW);
        const short8 b2 = *(const short8*)(bb + 32 * BROW);
        const short8 b3 = *(const short8*)(bb + 48 * BROW);
        union { unsigned u[4]; short8 v; } A0, A1;
#pragma unroll
        for (int e = 0; e < 4; ++e) {
          A0.u[e] = pack_bf2(s0 * jv0[h * 8 + 2 * e], s0 * jv0[h * 8 + 2 * e + 1]);
          A1.u[e] = pack_bf2(s1 * jv1[h * 8 + 2 * e], s1 * jv1[h * 8 + 2 * e + 1]);
        }
        acc0[0] = __builtin_amdgcn_mfma_f32_16x16x32_bf16(A0.v, b0, acc0[0], 0, 0, 0);
        acc0[1] = __builtin_amdgcn_mfma_f32_16x16x32_bf16(A0.v, b1, acc0[1], 0, 0, 0);
        acc0[2] = __builtin_amdgcn_mfma_f32_16x16x32_bf16(A0.v, b2, acc0[2], 0, 0, 0);
        acc0[3] = __builtin_amdgcn_mfma_f32_16x16x32_bf16(A0.v, b3, acc0[3], 0, 0, 0);
        acc1[0] = __builtin_amdgcn_mfma_f32_16x16x32_bf16(A1.v, b0, acc1[0], 0, 0, 0);
        acc1[1] = __builtin_amdgcn_mfma_f32_16x16x32_bf16(A1.v, b1, acc1[1], 0, 0, 0);
        acc1[2] = __builtin_amdgcn_mfma_f32_16x16x32_bf16(A1.v, b2, acc1[2], 0, 0, 0);
        acc1[3] = __builtin_amdgcn_mfma_f32_16x16x32_bf16(A1.v, b3, acc1[3], 0, 0, 0);
      }
    }
    // write prefetched chunk into the other buffer (disjoint from buffer being read)
    if (c + 1 < NCHUNK) {
      unsigned short* dst = ldsB[(c + 1) & 1];
#pragma unroll
      for (int it = 0; it < 4; ++it) {
        const int lin = tid + it * 256;
        const int row = lin >> 4;
        const int cc  = lin & 15;
        *(uint4*)(&dst[row * BROW + cc * 8]) = pre[it];
      }
    }
    __syncthreads();  // single barrier per chunk: publishes buf (c+1)&1, retires reads of buf c&1
  }

  // epilogue: C/D layout col=lane&15, row=q*4+r
  const int zr0 = zblk + wv * 32 + q * 4;
#pragma unroll
  for (int g = 0; g < 4; ++g) {
#pragma unroll
    for (int r = 0; r < 4; ++r) {
      out[(size_t)(zr0 + r) * 64 + g * 16 + m]      = acc0[g][r];
      out[(size_t)(zr0 + 16 + r) * 64 + g * 16 + m] = acc1[g][r];
    }
  }
}

extern "C" void kernel_launch(void* const* d_in, const int* in_sizes, int n_in,
                              void* d_out, int out_size, void* d_ws, size_t ws_size,
                              hipStream_t stream) {
  const float* X   = (const float*)d_in[0];   // [131072, 64]
  const float* mix = (const float*)d_in[1];   // [32, 64, 64, 64]
  const float* wgt = (const float*)d_in[2];   // [32]
  float* out = (float*)d_out;                 // [131072, 64]
  unsigned short* Bp = (unsigned short*)d_ws; // 512 KB scratch: M~ bf16 [64][4096]

  prep_kernel<<<256, 256, 0, stream>>>(mix, wgt, Bp);
  gemm_kernel<<<1024, 256, 0, stream>>>(X, Bp, out);
}

// Round 2
// 164.523 us; speedup vs baseline: 1.2112x; 1.2112x over previous
//
#include <hip/hip_runtime.h>
#include <stdint.h>

typedef __attribute__((ext_vector_type(8))) short short8;
typedef __attribute__((ext_vector_type(4))) float f32x4;

#define NCHUNK 64     // 4096 / 64 t-elements per chunk (one i-slice per chunk)
#define BROWS  72     // shorts per ldsB row (64 data + 8 pad; 144B, 16B-aligned)
#define XD     65     // dwords per ldsX row (64 z-pairs + 1 pad)

__device__ __forceinline__ unsigned short f2bf_rne(float f) {
  unsigned u = __builtin_bit_cast(unsigned, f);
  u += 0x7fffu + ((u >> 16) & 1u);
  return (unsigned short)(u >> 16);
}
__device__ __forceinline__ float bf2f(unsigned short s) {
  unsigned u = ((unsigned)s) << 16;
  return __builtin_bit_cast(float, u);
}
// pack two f32 -> two bf16 (truncate) in one v_perm_b32; lo short = p0
__device__ __forceinline__ unsigned pack_bf2(float p0, float p1) {
  return __builtin_amdgcn_perm(__builtin_bit_cast(unsigned, p1),
                               __builtin_bit_cast(unsigned, p0), 0x07060302u);
}

// ---- phase 1: M~[k][t] = sum_w wgt[w]*mix[w][k][t] -> bf16, 4-way w-split ----
__global__ __launch_bounds__(256) void prep_kernel(const float* __restrict__ mix,
                                                   const float* __restrict__ wgt,
                                                   unsigned short* __restrict__ Bp) {
  __shared__ float4 red[256];
  const int tid = threadIdx.x;
  const int ws  = tid >> 6;   // w-quarter 0..3
  const int tt  = tid & 63;
  const int t4  = blockIdx.x * 64 + tt;  // 0..65535 (4 t-elems each)
  const float4* m4 = (const float4*)mix;
  float ax = 0.f, ay = 0.f, az = 0.f, aw = 0.f;
#pragma unroll
  for (int wi = 0; wi < 8; ++wi) {
    const int w = ws * 8 + wi;
    const float s = wgt[w];
    const float4 v = m4[w * 65536 + t4];
    ax += s * v.x; ay += s * v.y; az += s * v.z; aw += s * v.w;
  }
  red[tid] = (float4){ax, ay, az, aw};
  __syncthreads();
  if (tid < 64) {
    const float4 a = red[tid], b = red[tid + 64], c = red[tid + 128], d = red[tid + 192];
    ushort4 r;
    r.x = f2bf_rne(a.x + b.x + c.x + d.x);
    r.y = f2bf_rne(a.y + b.y + c.y + d.y);
    r.z = f2bf_rne(a.z + b.z + c.z + d.z);
    r.w = f2bf_rne(a.w + b.w + c.w + d.w);
    ((ushort4*)Bp)[blockIdx.x * 64 + tid] = r;
  }
}

// ---- phase 2: out[z][k] = sum_t V[z,t]*M~[k,t], V generated in-register ----
// 128 threads (2 waves), each wave owns 64 z rows (4 MFMA z-frags), block = 128 z.
__global__ __launch_bounds__(128, 2) void gemm_kernel(const float* __restrict__ X,
                                                      const unsigned short* __restrict__ Bp,
                                                      float* __restrict__ out) {
  __shared__ unsigned short ldsB[2][64 * BROWS];  // double-buffered B chunk [k][t-slice]
  __shared__ unsigned ldsX[64 * XD];              // [i][z-pair] packed bf16 (lo=even z)

  const int tid  = threadIdx.x;
  const int lane = tid & 63;
  const int wv   = tid >> 6;    // wave 0..1 -> z rows wv*64..+63
  const int m    = lane & 15;
  const int q    = lane >> 4;
  const int zblk = blockIdx.x * 128;

  // ---- stage X tile [64 i][128 z] as bf16 z-pairs (2-way banks only) ----
  {
    const float4* X4 = (const float4*)(X + (size_t)zblk * 64);
#pragma unroll
    for (int it = 0; it < 8; ++it) {
      const int lin = tid + it * 128;  // 0..1023
      const int zz  = lin >> 4;        // z-pair 0..63
      const int c4  = lin & 15;        // float4 col 0..15
      const float4 v0 = X4[(2 * zz) * 16 + c4];
      const float4 v1 = X4[(2 * zz + 1) * 16 + c4];
      float a0[4], a1[4];
      *(float4*)a0 = v0; *(float4*)a1 = v1;
#pragma unroll
      for (int r = 0; r < 4; ++r) {
        const unsigned pk = (unsigned)f2bf_rne(a0[r]) | ((unsigned)f2bf_rne(a1[r]) << 16);
        ldsX[(c4 * 4 + r) * XD + zz] = pk;
      }
    }
  }
  // ---- stage B chunk 0 into buf 0 ----
  {
#pragma unroll
    for (int it = 0; it < 4; ++it) {
      const int lin = tid + it * 128;  // 0..511
      const int row = lin >> 3;        // k 0..63
      const int cc  = lin & 7;
      const uint4 v = *(const uint4*)(Bp + row * 4096 + cc * 8);
      *(uint4*)(&ldsB[0][row * BROWS + cc * 8]) = v;
    }
  }

  // ---- per-lane fp32 j-cache: jv[f][h*8+e] = x[z(f,m), h*32 + q*8 + e] ----
  float jv[4][16];
  {
    const float4* X4g = (const float4*)X;
#pragma unroll
    for (int f = 0; f < 4; ++f) {
      const int zg = zblk + wv * 64 + f * 16 + m;
#pragma unroll
      for (int h = 0; h < 2; ++h) {
        const float4 a = X4g[zg * 16 + h * 8 + q * 2];
        const float4 b = X4g[zg * 16 + h * 8 + q * 2 + 1];
        jv[f][h*8+0]=a.x; jv[f][h*8+1]=a.y; jv[f][h*8+2]=a.z; jv[f][h*8+3]=a.w;
        jv[f][h*8+4]=b.x; jv[f][h*8+5]=b.y; jv[f][h*8+6]=b.z; jv[f][h*8+7]=b.w;
      }
    }
  }

  f32x4 acc[4][4];
#pragma unroll
  for (int f = 0; f < 4; ++f)
#pragma unroll
    for (int g = 0; g < 4; ++g) acc[f][g] = f32x4{0.f, 0.f, 0.f, 0.f};

  __syncthreads();

  const unsigned short* xs = (const unsigned short*)ldsX;

  for (int c = 0; c < NCHUNK; ++c) {
    // prefetch next B chunk global(L2) -> regs; hidden under the MFMAs below
    uint4 pre[4];
    const int cn = (c + 1) & (NCHUNK - 1);
#pragma unroll
    for (int it = 0; it < 4; ++it) {
      const int lin = tid + it * 128;
      const int row = lin >> 3;
      const int cc  = lin & 7;
      pre[it] = *(const uint4*)(Bp + row * 4096 + cn * 64 + cc * 8);
    }

    // s[f] = x[z(f,m), i=c] (bf16 broadcast from ldsX)
    float s[4];
#pragma unroll
    for (int f = 0; f < 4; ++f)
      s[f] = bf2f(xs[c * (2 * XD) + wv * 64 + f * 16 + m]);

    const unsigned short* Bl = ldsB[c & 1];
#pragma unroll
    for (int h = 0; h < 2; ++h) {
      const unsigned short* bb = Bl + m * BROWS + h * 32 + q * 8;
      const short8 b0 = *(const short8*)(bb);
      const short8 b1 = *(const short8*)(bb + 16 * BROWS);
      const short8 b2 = *(const short8*)(bb + 32 * BROWS);
      const short8 b3 = *(const short8*)(bb + 48 * BROWS);
#pragma unroll
      for (int f = 0; f < 4; ++f) {
        union { unsigned u[4]; short8 v; } A;
#pragma unroll
        for (int e = 0; e < 4; ++e)
          A.u[e] = pack_bf2(s[f] * jv[f][h * 8 + 2 * e], s[f] * jv[f][h * 8 + 2 * e + 1]);
        acc[f][0] = __builtin_amdgcn_mfma_f32_16x16x32_bf16(A.v, b0, acc[f][0], 0, 0, 0);
        acc[f][1] = __builtin_amdgcn_mfma_f32_16x16x32_bf16(A.v, b1, acc[f][1], 0, 0, 0);
        acc[f][2] = __builtin_amdgcn_mfma_f32_16x16x32_bf16(A.v, b2, acc[f][2], 0, 0, 0);
        acc[f][3] = __builtin_amdgcn_mfma_f32_16x16x32_bf16(A.v, b3, acc[f][3], 0, 0, 0);
      }
    }

    // publish prefetched chunk into the other buffer (disjoint from the one just read)
    {
      unsigned short* dst = ldsB[(c + 1) & 1];
#pragma unroll
      for (int it = 0; it < 4; ++it) {
        const int lin = tid + it * 128;
        const int row = lin >> 3;
        const int cc  = lin & 7;
        *(uint4*)(&dst[row * BROWS + cc * 8]) = pre[it];
      }
    }
    __syncthreads();
  }

  // ---- epilogue: C/D layout col=lane&15 (k), row=q*4+r (z) ----
#pragma unroll
  for (int f = 0; f < 4; ++f) {
    const int zr = zblk + wv * 64 + f * 16 + q * 4;
#pragma unroll
    for (int g = 0; g < 4; ++g)
#pragma unroll
      for (int r = 0; r < 4; ++r)
        out[(size_t)(zr + r) * 64 + g * 16 + m] = acc[f][g][r];
  }
}

extern "C" void kernel_launch(void* const* d_in, const int* in_sizes, int n_in,
                              void* d_out, int out_size, void* d_ws, size_t ws_size,
                              hipStream_t stream) {
  const float* X   = (const float*)d_in[0];   // [131072, 64]
  const float* mix = (const float*)d_in[1];   // [32, 64, 64, 64]
  const float* wgt = (const float*)d_in[2];   // [32]
  float* out = (float*)d_out;                 // [131072, 64]
  unsigned short* Bp = (unsigned short*)d_ws; // 512 KB scratch: M~ bf16 [64][4096]

  prep_kernel<<<1024, 256, 0, stream>>>(mix, wgt, Bp);
  gemm_kernel<<<1024, 128, 0, stream>>>(X, Bp, out);
}